// Round 18
// baseline (1023.668 us; speedup 1.0000x reference)
//
#include <hip/hip_runtime.h>
#include <hip/hip_bf16.h>

#define HIDN 1152
#define NHEAD 16
#define HDIM 72
#define LTOK 1024
#define MTOK 2048
#define MLPM 3072

typedef short bf16x8 __attribute__((ext_vector_type(8)));
typedef float f32x4 __attribute__((ext_vector_type(4)));

__device__ __forceinline__ void gload16(const void* g, void* l) {
    __builtin_amdgcn_global_load_lds(
        (const __attribute__((address_space(1))) void*)g,
        (__attribute__((address_space(3))) void*)l,
        16, 0, 0);
}

__device__ __forceinline__ short bfbits(float f) {
    __hip_bfloat16 h = __float2bfloat16(f);
    return *(short*)&h;
}
__device__ __forceinline__ float bff(short s) {
    return __bfloat162float(*(__hip_bfloat16*)&s);
}

// XCD-aware bijective block remap (T1, m204 form; requires nwg % 8 == 0)
__device__ __forceinline__ void xcd_swizzle(int& bx, int& by) {
    int gx = gridDim.x;
    int wgid = blockIdx.y * gx + blockIdx.x;
    int cpx = (gx * gridDim.y) >> 3;
    int nid = (wgid & 7) * cpx + (wgid >> 3);
    bx = nid % gx;
    by = nid / gx;
}

// ---------------- patch embed: x (B,4,64,64) -> hx (2048,1152) bf16 ----------------
__global__ __launch_bounds__(256) void k_patch(const float* __restrict__ x,
        const float* __restrict__ pw, const float* __restrict__ pb,
        __hip_bfloat16* __restrict__ h) {
    int m = blockIdx.x;            // 0..2047
    int b = m >> 10, l = m & 1023;
    int si = l >> 5, sj = l & 31;
    __shared__ float toks[16];
    int tid = threadIdx.x;
    if (tid < 16) {
        int pi = tid >> 3, pj = (tid >> 2) & 1, c = tid & 3;
        toks[tid] = x[((size_t)(b*4 + c)*64 + si*2 + pi)*64 + sj*2 + pj];
    }
    __syncthreads();
    for (int o = tid; o < HIDN; o += 256) {
        float acc = pb[o];
        #pragma unroll
        for (int kk = 0; kk < 16; ++kk) acc += toks[kk] * pw[kk*HIDN + o];
        h[(size_t)m*HIDN + o] = __float2bfloat16(acc);
    }
}

// ------- temb1 = silu(timestep_emb @ w1 + b1): grid (9,2), 2-way K-split in-block -------
__global__ __launch_bounds__(256) void k_temb1_v2(const float* __restrict__ t,
        const float* __restrict__ w1, const float* __restrict__ b1,
        float* __restrict__ temb1) {
    int jt = blockIdx.x, b = blockIdx.y;
    int tid = threadIdx.x;
    __shared__ float emb[256];
    __shared__ float red[128];
    float tv = t[b];
    if (tid < 128) { float f = __expf(-logf(10000.f) * (float)tid / 128.f);        emb[tid] = cosf(tv * f); }
    else           { float f = __expf(-logf(10000.f) * (float)(tid - 128) / 128.f); emb[tid] = sinf(tv * f); }
    __syncthreads();
    int o = jt*128 + (tid & 127), s = tid >> 7;
    float acc = 0.f;
    for (int k = s*128; k < s*128 + 128; ++k) acc += emb[k] * w1[(size_t)k*HIDN + o];
    if (s) red[tid & 127] = acc;
    __syncthreads();
    if (!s) {
        float v = acc + red[tid] + b1[o];
        temb1[b*HIDN + o] = v / (1.f + __expf(-v));
    }
}

// ------- csilu stage 1: partial[kz][b][o] = temb1[b] @ w2[kz-slice]: grid (9,4) -------
__global__ __launch_bounds__(256) void k_csilu_s1(const float* __restrict__ temb1,
        const float* __restrict__ w2, float* __restrict__ csilup) {
    int jt = blockIdx.x, kz = blockIdx.y;
    int tid = threadIdx.x;
    __shared__ float t1s[2][288];
    __shared__ float red[2][128];
    for (int i = tid; i < 576; i += 256)
        t1s[i/288][i%288] = temb1[(i/288)*HIDN + kz*288 + (i%288)];
    __syncthreads();
    int o = jt*128 + (tid & 127), s = tid >> 7;
    float a0 = 0.f, a1 = 0.f;
    for (int i = s*144; i < s*144 + 144; ++i) {
        float wv = w2[(size_t)(kz*288 + i)*HIDN + o];
        a0 += t1s[0][i]*wv; a1 += t1s[1][i]*wv;
    }
    if (s) { red[0][tid & 127] = a0; red[1][tid & 127] = a1; }
    __syncthreads();
    if (!s) {
        csilup[(kz*2 + 0)*HIDN + o] = a0 + red[0][tid];
        csilup[(kz*2 + 1)*HIDN + o] = a1 + red[1][tid];
    }
}

// ------- csilu stage 2: reduce + b2 + y_table[y] + silu: grid (9,2) x 128 -------
__global__ __launch_bounds__(128) void k_csilu_s2(const float* __restrict__ csilup,
        const float* __restrict__ b2, const float* __restrict__ ytab,
        const int* __restrict__ y, float* __restrict__ csilu) {
    int o = blockIdx.x*128 + threadIdx.x;
    int b = blockIdx.y;
    float acc = b2[o] + ytab[(size_t)y[b]*HIDN + o];
    #pragma unroll
    for (int kz = 0; kz < 4; ++kz) acc += csilup[(kz*2 + b)*HIDN + o];
    csilu[b*HIDN + o] = acc / (1.f + __expf(-acc));
}

// ------- conditioning stage 1: all adaln (4 layers x 4608) + fadaln (2304) cols -------
__global__ __launch_bounds__(256) void k_cond_s1(const float* __restrict__ csilu,
        const float* __restrict__ adaln_w, const float* __restrict__ fadaln_w,
        float* __restrict__ condp) {
    int ct = blockIdx.x, kz = blockIdx.y;
    int tid = threadIdx.x;
    int c0 = ct*128;
    const float* Wb; int rstride;
    if (c0 < 18432) { int d = c0/4608; Wb = adaln_w + (size_t)d*HIDN*4608 + (c0 % 4608); rstride = 4608; }
    else            { Wb = fadaln_w + (c0 - 18432); rstride = 2304; }
    __shared__ float cs[2][288];
    __shared__ float red[2][128];
    for (int i = tid; i < 576; i += 256)
        cs[i/288][i%288] = csilu[(i/288)*HIDN + kz*288 + (i%288)];
    __syncthreads();
    int o = tid & 127, s = tid >> 7;
    float a0 = 0.f, a1 = 0.f;
    for (int i = s*144; i < s*144 + 144; ++i) {
        float wv = Wb[(size_t)(kz*288 + i)*rstride + o];
        a0 += cs[0][i]*wv; a1 += cs[1][i]*wv;
    }
    if (s) { red[0][o] = a0; red[1][o] = a1; }
    __syncthreads();
    if (!s) {
        condp[((size_t)kz*2 + 0)*20736 + c0 + o] = a0 + red[0][o];
        condp[((size_t)kz*2 + 1)*20736 + c0 + o] = a1 + red[1][o];
    }
}

// ------- conditioning stage 2: reduce 4 partials + bias -> modb / fmod: grid (81,2) -------
__global__ __launch_bounds__(256) void k_cond_s2(const float* __restrict__ condp,
        const float* __restrict__ adaln_b, const float* __restrict__ fadaln_b,
        float* __restrict__ modb, float* __restrict__ fmod) {
    int c = blockIdx.x*256 + threadIdx.x;
    int b = blockIdx.y;
    float acc = 0.f;
    #pragma unroll
    for (int kz = 0; kz < 4; ++kz) acc += condp[((size_t)kz*2 + b)*20736 + c];
    if (c < 18432) {
        int d = c/4608, j = c%4608;
        modb[((size_t)d*2 + b)*4608 + j] = acc + adaln_b[(size_t)d*4608 + j];
    } else {
        int j = c - 18432;
        fmod[(size_t)b*2304 + j] = acc + fadaln_b[j];
    }
}

// ---------------- RoPE tables (1024, 72) ----------------
__global__ __launch_bounds__(256) void k_rope(float* __restrict__ cosb, float* __restrict__ sinb) {
    int idx = blockIdx.x*256 + threadIdx.x;
    if (idx >= LTOK*HDIM) return;
    int l = idx / HDIM, dd = idx % HDIM;
    int i = l >> 5, j = l & 31;
    int pos = (dd < 36) ? i : j;
    int mm = ((dd < 36) ? dd : dd - 36) >> 1;
    float f = __expf(-logf(10000.f) * (float)mm / 18.f);
    float fr = (float)pos * f;
    cosb[idx] = cosf(fr);
    sinb[idx] = sinf(fr);
}

// ---------------- rmsnorm * (1 + s_mod): bf16 hx -> bf16 out ----------------
__global__ __launch_bounds__(256) void k_rms(const __hip_bfloat16* __restrict__ hx,
        const float* __restrict__ nw, const float* __restrict__ smod,
        __hip_bfloat16* __restrict__ outp) {
    int m = blockIdx.x; int b = m >> 10;
    int tid = threadIdx.x;
    const bf16x8* row8 = (const bf16x8*)(hx + (size_t)m*HIDN);
    bool act = tid < 144;              // 144 * 8 = 1152
    float vals[8];
    float part = 0.f;
    if (act) {
        bf16x8 v = row8[tid];
        #pragma unroll
        for (int i = 0; i < 8; ++i) { float f = bff(v[i]); vals[i] = f; part += f*f; }
    }
    for (int off = 32; off; off >>= 1) part += __shfl_xor(part, off);
    __shared__ float wsum[4];
    if ((tid & 63) == 0) wsum[tid >> 6] = part;
    __syncthreads();
    float rs = rsqrtf((wsum[0]+wsum[1]+wsum[2]+wsum[3]) * (1.f/HIDN) + 1e-6f);
    if (act) {
        const float* nwp = nw + tid*8;
        const float* sbp = smod + (size_t)b*4608 + tid*8;
        bf16x8 o;
        #pragma unroll
        for (int i = 0; i < 8; ++i)
            o[i] = bfbits(vals[i] * rs * nwp[i] * (1.f + sbp[i]));
        *(bf16x8*)(outp + (size_t)m*HIDN + tid*8) = o;
    }
}

// ------- cast+transpose ALL layer weights, 128k x 64n tiles, 256B reads AND writes -------
__global__ __launch_bounds__(256, 4) void k_castT_all(
        const float* __restrict__ qkv_w, const float* __restrict__ out_w,
        const float* __restrict__ m12_w, const float* __restrict__ m3_w,
        __hip_bfloat16* __restrict__ wtb) {
    __shared__ float tile[128][65];
    int bid = blockIdx.x;
    int layer = bid / 1944, r = bid % 1944;
    const float* W; __hip_bfloat16* Wt; int K, N, nt, t; bool glu = false;
    __hip_bfloat16* bl = wtb + (size_t)layer*15925248;
    if (r < 486)       { t = r;        nt = 54; K = 1152; N = 3456; W = qkv_w + (size_t)layer*K*N; Wt = bl; }
    else if (r < 648)  { t = r - 486;  nt = 18; K = 1152; N = 1152; W = out_w + (size_t)layer*K*N; Wt = bl + 3981312; }
    else if (r < 1512) { t = r - 648;  nt = 96; K = 1152; N = 6144; W = m12_w + (size_t)layer*K*N; Wt = bl + 5308416; glu = true; }
    else               { t = r - 1512; nt = 18; K = 3072; N = 1152; W = m3_w  + (size_t)layer*K*N; Wt = bl + 12386304; }
    int n0 = (t % nt)*64, k0 = (t / nt)*128;
    int tid = threadIdx.x;
    int rr = tid >> 4, c4 = (tid & 15)*4;
    #pragma unroll
    for (int p = 0; p < 8; ++p) {
        int kk = p*16 + rr;
        float4 v = *(const float4*)(W + (size_t)(k0+kk)*N + n0 + c4);
        tile[kk][c4+0] = v.x; tile[kk][c4+1] = v.y; tile[kk][c4+2] = v.z; tile[kk][c4+3] = v.w;
    }
    __syncthreads();
    int seg = tid & 15, nn0 = tid >> 4;
    #pragma unroll
    for (int p = 0; p < 4; ++p) {
        int nn = p*16 + nn0;
        bf16x8 o;
        #pragma unroll
        for (int j = 0; j < 8; ++j) o[j] = bfbits(tile[seg*8 + j][nn]);
        int ng = n0 + nn;
        int np = glu ? ((ng < 3072) ? 2*ng : 2*(ng - 3072) + 1) : ng;
        *(bf16x8*)(Wt + (size_t)np*K + k0 + seg*8) = o;
    }
}

// ---------------- bf16 MFMA GEMM 128x128, double-buffered ------
// EPI 0: C = bf16(A@W^T + bias)   EPI 2: GLU interleaved -> bf16(silu(x1)*x2), ld=N/2
template<int EPI, typename OutT>
__global__ __launch_bounds__(256) void k_gemm_bf16(
        const __hip_bfloat16* __restrict__ A,
        const __hip_bfloat16* __restrict__ Wt,
        const float* __restrict__ bias,
        OutT* __restrict__ C, int M, int N, int K,
        const float* __restrict__ gate) {
    __shared__ __hip_bfloat16 Asm[2][128*64];
    __shared__ __hip_bfloat16 Bsm[2][128*64];
    int bx, by; xcd_swizzle(bx, by);
    int tid = threadIdx.x;
    int lane = tid & 63, w = tid >> 6;
    int wr = w >> 1, wc = w & 1;
    int m0 = by * 128, n0 = bx * 128;
    f32x4 acc[4][4] = {};
    int lr = lane >> 3, ls = lane & 7;
    int swz = ls ^ (lr & 7);
    int x7 = lane & 7;
    const __hip_bfloat16* Ag = A  + (size_t)(m0 + lr)*K + swz*8;
    const __hip_bfloat16* Bg = Wt + (size_t)(n0 + lr)*K + swz*8;
    int nk = K >> 6;
    #pragma unroll
    for (int i = 0; i < 4; ++i) {
        int seg = w*4 + i;
        gload16(Ag + (size_t)(seg*8)*K, (char*)&Asm[0][0] + seg*1024);
        gload16(Bg + (size_t)(seg*8)*K, (char*)&Bsm[0][0] + seg*1024);
    }
    __syncthreads();
    for (int t = 0; t < nk; ++t) {
        int cur = t & 1;
        if (t + 1 < nk) {
            int k1 = (t + 1) << 6;
            #pragma unroll
            for (int i = 0; i < 4; ++i) {
                int seg = w*4 + i;
                gload16(Ag + (size_t)(seg*8)*K + k1, (char*)&Asm[cur^1][0] + seg*1024);
                gload16(Bg + (size_t)(seg*8)*K + k1, (char*)&Bsm[cur^1][0] + seg*1024);
            }
        }
        const __hip_bfloat16* Ac = Asm[cur];
        const __hip_bfloat16* Bc = Bsm[cur];
        __builtin_amdgcn_s_setprio(1);
        #pragma unroll
        for (int kk = 0; kk < 2; ++kk) {
            bf16x8 af[4], bfr[4];
            #pragma unroll
            for (int m = 0; m < 4; ++m) {
                int row = wr*64 + m*16 + (lane&15);
                af[m] = *(const bf16x8*)(Ac + row*64 + (((kk*4 + (lane>>4)) ^ x7) * 8));
            }
            #pragma unroll
            for (int n = 0; n < 4; ++n) {
                int col = wc*64 + n*16 + (lane&15);
                bfr[n] = *(const bf16x8*)(Bc + col*64 + (((kk*4 + (lane>>4)) ^ x7) * 8));
            }
            #pragma unroll
            for (int m = 0; m < 4; ++m)
                #pragma unroll
                for (int n = 0; n < 4; ++n)
                    acc[m][n] = __builtin_amdgcn_mfma_f32_16x16x32_bf16(af[m], bfr[n], acc[m][n], 0, 0, 0);
        }
        __builtin_amdgcn_s_setprio(0);
        __syncthreads();
    }
    int r0 = (lane >> 4) * 4;
    int ccol = lane & 15;
    #pragma unroll
    for (int m = 0; m < 4; ++m) {
        #pragma unroll
        for (int rr = 0; rr < 4; ++rr) {
            int row = m0 + wr*64 + m*16 + r0 + rr;
            #pragma unroll
            for (int n = 0; n < 4; ++n) {
                int col = n0 + wc*64 + n*16 + ccol;
                if (EPI == 0) {
                    float val = acc[m][n][rr] + bias[col];
                    C[(size_t)row*N + col] = (OutT)__float2bfloat16(val);
                } else {
                    float val = acc[m][n][rr] + bias[(col & 1) ? 3072 + (col >> 1) : (col >> 1)];
                    float other = __shfl_xor(val, 1);
                    if (!(lane & 1)) {
                        float res = val / (1.f + __expf(-val)) * other;
                        ((__hip_bfloat16*)C)[(size_t)row*(N>>1) + (col>>1)] = __float2bfloat16(res);
                    }
                }
            }
        }
    }
}

// ------- qkv GEMM 128x128, double-buffered, fused RoPE + q/k/v-split epilogue -------
__global__ __launch_bounds__(256) void k_gemm_qkv(
        const __hip_bfloat16* __restrict__ A,
        const __hip_bfloat16* __restrict__ Wt,
        const float* __restrict__ bias,
        const float* __restrict__ cosb, const float* __restrict__ sinb,
        __hip_bfloat16* __restrict__ q, __hip_bfloat16* __restrict__ k,
        __hip_bfloat16* __restrict__ v) {
    const int N = 3456, K = HIDN;
    __shared__ __hip_bfloat16 Asm[2][128*64];
    __shared__ __hip_bfloat16 Bsm[2][128*64];
    int bx, by; xcd_swizzle(bx, by);
    int tid = threadIdx.x;
    int lane = tid & 63, w = tid >> 6;
    int wr = w >> 1, wc = w & 1;
    int m0 = by * 128, n0 = bx * 128;
    f32x4 acc[4][4] = {};
    int lr = lane >> 3, ls = lane & 7;
    int swz = ls ^ (lr & 7);
    int x7 = lane & 7;
    const __hip_bfloat16* Ag = A  + (size_t)(m0 + lr)*K + swz*8;
    const __hip_bfloat16* Bg = Wt + (size_t)(n0 + lr)*K + swz*8;
    const int nk = K >> 6;
    #pragma unroll
    for (int i = 0; i < 4; ++i) {
        int seg = w*4 + i;
        gload16(Ag + (size_t)(seg*8)*K, (char*)&Asm[0][0] + seg*1024);
        gload16(Bg + (size_t)(seg*8)*K, (char*)&Bsm[0][0] + seg*1024);
    }
    __syncthreads();
    for (int t = 0; t < nk; ++t) {
        int cur = t & 1;
        if (t + 1 < nk) {
            int k1 = (t + 1) << 6;
            #pragma unroll
            for (int i = 0; i < 4; ++i) {
                int seg = w*4 + i;
                gload16(Ag + (size_t)(seg*8)*K + k1, (char*)&Asm[cur^1][0] + seg*1024);
                gload16(Bg + (size_t)(seg*8)*K + k1, (char*)&Bsm[cur^1][0] + seg*1024);
            }
        }
        const __hip_bfloat16* Ac = Asm[cur];
        const __hip_bfloat16* Bc = Bsm[cur];
        __builtin_amdgcn_s_setprio(1);
        #pragma unroll
        for (int kk = 0; kk < 2; ++kk) {
            bf16x8 af[4], bfr[4];
            #pragma unroll
            for (int m = 0; m < 4; ++m) {
                int row = wr*64 + m*16 + (lane&15);
                af[m] = *(const bf16x8*)(Ac + row*64 + (((kk*4 + (lane>>4)) ^ x7) * 8));
            }
            #pragma unroll
            for (int n = 0; n < 4; ++n) {
                int col = wc*64 + n*16 + (lane&15);
                bfr[n] = *(const bf16x8*)(Bc + col*64 + (((kk*4 + (lane>>4)) ^ x7) * 8));
            }
            #pragma unroll
            for (int m = 0; m < 4; ++m)
                #pragma unroll
                for (int n = 0; n < 4; ++n)
                    acc[m][n] = __builtin_amdgcn_mfma_f32_16x16x32_bf16(af[m], bfr[n], acc[m][n], 0, 0, 0);
        }
        __builtin_amdgcn_s_setprio(0);
        __syncthreads();
    }
    int r0 = (lane >> 4) * 4;
    int ccol = lane & 15;
    int sec = n0 / 1152;            // 0=q 1=k 2=v, block-uniform
    int rembase = n0 - sec*1152 + wc*64;
    #pragma unroll
    for (int m = 0; m < 4; ++m) {
        #pragma unroll
        for (int rr = 0; rr < 4; ++rr) {
            int row = m0 + wr*64 + m*16 + r0 + rr;
            int b = row >> 10, l = row & 1023;
            #pragma unroll
            for (int n = 0; n < 4; ++n) {
                int rem = rembase + n*16 + ccol;
                int h = rem / HDIM, d = rem % HDIM;
                float val = acc[m][n][rr] + bias[sec*1152 + rem];
                if (sec == 2) {
                    v[((size_t)(b*NHEAD + h)*HDIM + d)*LTOK + l] = __float2bfloat16(val);
                } else {
                    float c = cosb[l*HDIM + d], s = sinb[l*HDIM + d];
                    float other = __shfl_xor(val, 1);
                    float res = (d & 1) ? (val*c + other*s) : (val*c - other*s);
                    __hip_bfloat16 hv = __float2bfloat16(res);
                    size_t dst = ((size_t)(b*NHEAD + h)*LTOK + l)*HDIM + d;
                    if (sec == 0) q[dst] = hv; else k[dst] = hv;
                }
            }
        }
    }
}

// ------- bf16 MFMA GEMM 32x128 tile (max occupancy for N=1152), EPI1 bf16 RMW ---
__global__ __launch_bounds__(256) void k_gemm32(
        const __hip_bfloat16* __restrict__ A,
        const __hip_bfloat16* __restrict__ Wt,
        const float* __restrict__ bias,
        __hip_bfloat16* __restrict__ C, int M, int N, int K,
        const float* __restrict__ gate) {
    __shared__ __hip_bfloat16 Asm[2][32*64];
    __shared__ __hip_bfloat16 Bsm[2][128*64];
    int bx, by; xcd_swizzle(bx, by);
    int tid = threadIdx.x;
    int lane = tid & 63, w = tid >> 6;
    int wr = w >> 1, wc = w & 1;
    int m0 = by * 32, n0 = bx * 128;
    f32x4 acc[4] = {};
    int lr = lane >> 3, ls = lane & 7;
    int swz = ls ^ (lr & 7);
    int x7 = lane & 7;
    const __hip_bfloat16* Ag = A  + (size_t)(m0 + lr)*K + swz*8;
    const __hip_bfloat16* Bg = Wt + (size_t)(n0 + lr)*K + swz*8;
    int nk = K >> 6;
    gload16(Ag + (size_t)(w*8)*K, (char*)&Asm[0][0] + w*1024);
    #pragma unroll
    for (int i = 0; i < 4; ++i) {
        int seg = w*4 + i;
        gload16(Bg + (size_t)(seg*8)*K, (char*)&Bsm[0][0] + seg*1024);
    }
    __syncthreads();
    for (int t = 0; t < nk; ++t) {
        int cur = t & 1;
        if (t + 1 < nk) {
            int k1 = (t + 1) << 6;
            gload16(Ag + (size_t)(w*8)*K + k1, (char*)&Asm[cur^1][0] + w*1024);
            #pragma unroll
            for (int i = 0; i < 4; ++i) {
                int seg = w*4 + i;
                gload16(Bg + (size_t)(seg*8)*K + k1, (char*)&Bsm[cur^1][0] + seg*1024);
            }
        }
        const __hip_bfloat16* Ac = Asm[cur];
        const __hip_bfloat16* Bc = Bsm[cur];
        __builtin_amdgcn_s_setprio(1);
        #pragma unroll
        for (int kk = 0; kk < 2; ++kk) {
            int row = wr*16 + (lane&15);
            bf16x8 af = *(const bf16x8*)(Ac + row*64 + (((kk*4 + (lane>>4)) ^ x7) * 8));
            #pragma unroll
            for (int n = 0; n < 4; ++n) {
                int col = wc*64 + n*16 + (lane&15);
                bf16x8 bfr = *(const bf16x8*)(Bc + col*64 + (((kk*4 + (lane>>4)) ^ x7) * 8));
                acc[n] = __builtin_amdgcn_mfma_f32_16x16x32_bf16(af, bfr, acc[n], 0, 0, 0);
            }
        }
        __builtin_amdgcn_s_setprio(0);
        __syncthreads();
    }
    int r0 = (lane >> 4) * 4;
    int ccol = lane & 15;
    #pragma unroll
    for (int rr = 0; rr < 4; ++rr) {
        int row = m0 + wr*16 + r0 + rr;
        int bi = row >> 10;
        #pragma unroll
        for (int n = 0; n < 4; ++n) {
            int col = n0 + wc*64 + n*16 + ccol;
            float val = acc[n][rr] + bias[col];
            size_t idx = (size_t)row*N + col;
            float prev = __bfloat162float(C[idx]);
            C[idx] = __float2bfloat16(prev + gate[(size_t)bi*4608 + col] * val);
        }
    }
}

// ------- MFMA flash attention: XCD-local heads + defer-max + packed P-stores ---------
__global__ __launch_bounds__(512) void k_attn_mfma(
        const __hip_bfloat16* __restrict__ q,
        const __hip_bfloat16* __restrict__ k,
        const __hip_bfloat16* __restrict__ vt,
        __hip_bfloat16* __restrict__ o) {
    int x = blockIdx.x;
    int head_id = (x & 7)*4 + (x >> 6);   // 0..31; constant per XCD slice
    int qt = (x >> 3) & 7;
    int b = head_id >> 4, h = head_id & 15;
    const float scale = 0.117851130f;   // 1/sqrt(72)
    __shared__ __hip_bfloat16 Ksm[2][64*72];
    __shared__ __hip_bfloat16 Vsm[2][72*64];
    __shared__ __hip_bfloat16 Psm[8][16*72];
    int tid = threadIdx.x, lane = tid & 63, w = tid >> 6;   // w: 0..7
    int l15 = lane & 15, g = lane >> 4;
    const __hip_bfloat16* qg = q  + ((size_t)(b*NHEAD + h)*LTOK + qt*128)*HDIM;
    const __hip_bfloat16* kg = k  + (size_t)(b*NHEAD + h)*LTOK*HDIM;
    const __hip_bfloat16* vg = vt + (size_t)(b*NHEAD + h)*HDIM*LTOK;
    const bf16x8 z = {};

    bf16x8 qf[3];
    {
        const __hip_bfloat16* qrow = qg + (w*16 + l15)*HDIM;
        qf[0] = *(const bf16x8*)(qrow + g*8);
        qf[1] = *(const bf16x8*)(qrow + 32 + g*8);
        qf[2] = (g == 0) ? *(const bf16x8*)(qrow + 64) : z;
    }
    int vsw  = ((lane & 7) ^ (lane >> 3)) * 8;
    int vrow = lane >> 3;

    f32x4 oacc[5] = {};
    float mold[4] = {-1e30f, -1e30f, -1e30f, -1e30f};
    float lsum[4] = {};

    {
        for (int s = w; s < 9; s += 8) {
            gload16(kg + s*512 + lane*8, (char*)&Ksm[0][0] + s*1024);
            gload16(vg + (size_t)(s*8 + vrow)*LTOK + vsw, (char*)&Vsm[0][0] + s*1024);
        }
    }
    __syncthreads();

    for (int kt2 = 0; kt2 < 16; ++kt2) {
        int cur = kt2 & 1;
        if (kt2 < 15) {
            const __hip_bfloat16* ktg = kg + (size_t)(kt2+1)*64*HDIM;
            const __hip_bfloat16* vtg = vg + (kt2+1)*64;
            for (int s = w; s < 9; s += 8) {
                gload16(ktg + s*512 + lane*8, (char*)&Ksm[cur^1][0] + s*1024);
                gload16(vtg + (size_t)(s*8 + vrow)*LTOK + vsw, (char*)&Vsm[cur^1][0] + s*1024);
            }
        }
        const __hip_bfloat16* Kc = Ksm[cur];
        const __hip_bfloat16* Vc = Vsm[cur];
        f32x4 st[4] = {};
        __builtin_amdgcn_s_setprio(1);
        #pragma unroll
        for (int t = 0; t < 4; ++t) {
            const __hip_bfloat16* krow = Kc + (t*16 + l15)*72;
            bf16x8 kf0 = *(const bf16x8*)(krow + g*8);
            bf16x8 kf1 = *(const bf16x8*)(krow + 32 + g*8);
            bf16x8 kf2 = (g == 0) ? *(const bf16x8*)(krow + 64) : z;
            st[t] = __builtin_amdgcn_mfma_f32_16x16x32_bf16(qf[0], kf0, st[t], 0, 0, 0);
            st[t] = __builtin_amdgcn_mfma_f32_16x16x32_bf16(qf[1], kf1, st[t], 0, 0, 0);
            st[t] = __builtin_amdgcn_mfma_f32_16x16x32_bf16(qf[2], kf2, st[t], 0, 0, 0);
        }
        __builtin_amdgcn_s_setprio(0);
        float mtr[4];
        #pragma unroll
        for (int r = 0; r < 4; ++r) {
            float mt = fmaxf(fmaxf(st[0][r], st[1][r]), fmaxf(st[2][r], st[3][r]));
            mt = fmaxf(mt, __shfl_xor(mt, 1));
            mt = fmaxf(mt, __shfl_xor(mt, 2));
            mt = fmaxf(mt, __shfl_xor(mt, 4));
            mt = fmaxf(mt, __shfl_xor(mt, 8));
            mtr[r] = mt;
        }
        bool need = false;
        #pragma unroll
        for (int r = 0; r < 4; ++r) need |= (mtr[r] - mold[r]) * scale > 8.f;
        if (__any(need)) {
            #pragma unroll
            for (int r = 0; r < 4; ++r) {
                float mn = fmaxf(mold[r], mtr[r]);
                float corr = __expf((mold[r] - mn) * scale);
                mold[r] = mn;
                lsum[r] *= corr;
                #pragma unroll
                for (int dt = 0; dt < 5; ++dt) oacc[dt][r] *= corr;
            }
        }
        #pragma unroll
        for (int r = 0; r < 4; ++r) {
            float pv[4];
            float rs = 0.f;
            #pragma unroll
            for (int t = 0; t < 4; ++t) {
                pv[t] = __expf((st[t][r] - mold[r]) * scale);   // bounded by e^8
                rs += pv[t];
            }
            // packed P store: even l15 lanes write self|partner as one 4B word
            #pragma unroll
            for (int t = 0; t < 4; ++t) {
                float po = __shfl_xor(pv[t], 1);
                if (!(l15 & 1)) {
                    unsigned int packed = (unsigned int)(unsigned short)bfbits(pv[t])
                                        | ((unsigned int)(unsigned short)bfbits(po) << 16);
                    *(unsigned int*)(&Psm[w][(g*4 + r)*72 + t*16 + l15]) = packed;
                }
            }
            rs += __shfl_xor(rs, 1);
            rs += __shfl_xor(rs, 2);
            rs += __shfl_xor(rs, 4);
            rs += __shfl_xor(rs, 8);
            lsum[r] += rs;
        }
        bf16x8 pa0 = *(const bf16x8*)(&Psm[w][l15*72 + g*8]);
        bf16x8 pa1 = *(const bf16x8*)(&Psm[w][l15*72 + 32 + g*8]);
        int cswz = (l15 & 7)*8;
        __builtin_amdgcn_s_setprio(1);
        #pragma unroll
        for (int dt = 0; dt < 5; ++dt) {
            int row = dt*16 + l15;
            bool valid = (dt < 4) | (l15 < 8);
            bf16x8 vf0 = valid ? *(const bf16x8*)(Vc + row*64 + ((g*8) ^ cswz)) : z;
            bf16x8 vf1 = valid ? *(const bf16x8*)(Vc + row*64 + ((32 + g*8) ^ cswz)) : z;
            oacc[dt] = __builtin_amdgcn_mfma_f32_16x16x32_bf16(pa0, vf0, oacc[dt], 0, 0, 0);
            oacc[dt] = __builtin_amdgcn_mfma_f32_16x16x32_bf16(pa1, vf1, oacc[dt], 0, 0, 0);
        }
        __builtin_amdgcn_s_setprio(0);
        __syncthreads();
    }
    #pragma unroll
    for (int r = 0; r < 4; ++r) {
        float inv = 1.f / lsum[r];
        int row = qt*128 + w*16 + g*4 + r;
        __hip_bfloat16* op = o + ((size_t)b*LTOK + row)*HIDN + h*HDIM;
        #pragma unroll
        for (int dt = 0; dt < 5; ++dt) {
            int d = dt*16 + l15;
            if (d < HDIM) op[d] = __float2bfloat16(oacc[dt][r] * inv);
        }
    }
}

// ---------------- final norm + linear + unpatchify (bf16 hx) ----------------
__global__ __launch_bounds__(256) void k_final(const __hip_bfloat16* __restrict__ hx,
        const float* __restrict__ fnw, const float* __restrict__ fmod,
        const float* __restrict__ flw, const float* __restrict__ flb,
        float* __restrict__ out) {
    int m = blockIdx.x; int b = m >> 10, l = m & 1023;
    int tid = threadIdx.x;
    const bf16x8* row8 = (const bf16x8*)(hx + (size_t)m*HIDN);
    bool act = tid < 144;
    float vals[8];
    float part = 0.f;
    if (act) {
        bf16x8 v = row8[tid];
        #pragma unroll
        for (int i = 0; i < 8; ++i) { float f = bff(v[i]); vals[i] = f; part += f*f; }
    }
    for (int off = 32; off; off >>= 1) part += __shfl_xor(part, off);
    __shared__ float wsum[4];
    __shared__ float hfs[HIDN];
    __shared__ float red[4][16];
    if ((tid & 63) == 0) wsum[tid >> 6] = part;
    __syncthreads();
    float rs = rsqrtf((wsum[0]+wsum[1]+wsum[2]+wsum[3]) * (1.f/HIDN) + 1e-6f);
    if (act) {
        const float* fm = fmod + (size_t)b*2304;
        #pragma unroll
        for (int i = 0; i < 8; ++i) {
            int j = tid*8 + i;
            hfs[j] = vals[i] * rs * fnw[j] * (1.f + fm[HIDN + j]) + fm[j];
        }
    }
    __syncthreads();
    float pacc[16] = {};
    for (int j = tid; j < HIDN; j += 256) {
        float hv = hfs[j];
        #pragma unroll
        for (int kk = 0; kk < 16; ++kk) pacc[kk] += hv * flw[j*16 + kk];
    }
    #pragma unroll
    for (int kk = 0; kk < 16; ++kk)
        for (int off = 32; off; off >>= 1) pacc[kk] += __shfl_xor(pacc[kk], off);
    if ((tid & 63) == 0) {
        int w = tid >> 6;
        #pragma unroll
        for (int kk = 0; kk < 16; ++kk) red[w][kk] = pacc[kk];
    }
    __syncthreads();
    if (tid < 16) {
        float val = red[0][tid] + red[1][tid] + red[2][tid] + red[3][tid] + flb[tid];
        int pi = tid >> 3, pj = (tid >> 2) & 1, c = tid & 3;
        int si = l >> 5, sj = l & 31;
        out[((size_t)(b*4 + c)*64 + si*2 + pi)*64 + sj*2 + pj] = val;
    }
}

extern "C" void kernel_launch(void* const* d_in, const int* in_sizes, int n_in,
                              void* d_out, int out_size, void* d_ws, size_t ws_size,
                              hipStream_t stream) {
    const float* x        = (const float*)d_in[0];
    const float* t        = (const float*)d_in[1];
    const int*   y        = (const int*)  d_in[2];
    const float* patch_w  = (const float*)d_in[3];
    const float* patch_b  = (const float*)d_in[4];
    const float* t_w1     = (const float*)d_in[5];
    const float* t_b1     = (const float*)d_in[6];
    const float* t_w2     = (const float*)d_in[7];
    const float* t_b2     = (const float*)d_in[8];
    const float* y_table  = (const float*)d_in[9];
    const float* norm1_w  = (const float*)d_in[10];
    const float* qkv_w    = (const float*)d_in[11];
    const float* qkv_b    = (const float*)d_in[12];
    const float* out_w    = (const float*)d_in[13];
    const float* out_b    = (const float*)d_in[14];
    const float* norm2_w  = (const float*)d_in[15];
    const float* mlp_w12  = (const float*)d_in[16];
    const float* mlp_b12  = (const float*)d_in[17];
    const float* mlp_w3   = (const float*)d_in[18];
    const float* mlp_b3   = (const float*)d_in[19];
    const float* adaln_w  = (const float*)d_in[20];
    const float* adaln_b  = (const float*)d_in[21];
    const float* fnorm_w  = (const float*)d_in[22];
    const float* fadaln_w = (const float*)d_in[23];
    const float* fadaln_b = (const float*)d_in[24];
    const float* flin_w   = (const float*)d_in[25];
    const float* flin_b   = (const float*)d_in[26];

    char* base = (char*)d_ws;
    __hip_bfloat16* hx    = (__hip_bfloat16*)(base);              //  4,718,592 B (bf16 residual)
    __hip_bfloat16* qbf   = (__hip_bfloat16*)(base + 34603008);   //  4,718,592 B
    __hip_bfloat16* kbf   = (__hip_bfloat16*)(base + 39321600);   //  4,718,592 B
    __hip_bfloat16* vbf   = (__hip_bfloat16*)(base + 44040192);   //  4,718,592 B (B,NH,72,L)
    __hip_bfloat16* hbf   = (__hip_bfloat16*)(base + 48758784);   //  4,718,592 B
    __hip_bfloat16* mhbf  = qbf;                                  // GLU out aliases q/k (consumed)
    __hip_bfloat16* wtb   = (__hip_bfloat16*)(base + 53477376);   // 127,401,984 B (4 layers)
    float* temb1 = (float*)(base + 180879360);       // 9216 B
    float* csilu = (float*)(base + 180888576);       // 9216 B
    float* modb  = (float*)(base + 180897792);       // 147456 B [4][2][4608]
    float* fmod  = (float*)(base + 181045248);       // 18432 B  [2][2304]
    float* cosb  = (float*)(base + 181063680);       // 294912 B
    float* sinb  = (float*)(base + 181358592);       // 294912 B
    float* condp = (float*)(base + 181653504);       // 663552 B [4][2][20736]
    float* csilup= (float*)(base + 182317056);       // 36864 B
    // total ~182.4 MB

    k_patch<<<2048, 256, 0, stream>>>(x, patch_w, patch_b, hx);
    k_temb1_v2<<<dim3(9,2), 256, 0, stream>>>(t, t_w1, t_b1, temb1);
    k_csilu_s1<<<dim3(9,4), 256, 0, stream>>>(temb1, t_w2, csilup);
    k_csilu_s2<<<dim3(9,2), 128, 0, stream>>>(csilup, t_b2, y_table, y, csilu);
    k_cond_s1<<<dim3(162,4), 256, 0, stream>>>(csilu, adaln_w, fadaln_w, condp);
    k_cond_s2<<<dim3(81,2), 256, 0, stream>>>(condp, adaln_b, fadaln_b, modb, fmod);
    k_rope<<<288, 256, 0, stream>>>(cosb, sinb);
    k_castT_all<<<7776, 256, 0, stream>>>(qkv_w, out_w, mlp_w12, mlp_w3, wtb);

    for (int d = 0; d < 4; ++d) {
        const float* modd = modb + (size_t)d*2*4608;
        __hip_bfloat16* wl = wtb + (size_t)d*15925248;
        __hip_bfloat16* wt_qkv = wl;
        __hip_bfloat16* wt_out = wl + 3981312;
        __hip_bfloat16* wt_m12 = wl + 5308416;
        __hip_bfloat16* wt_m3  = wl + 12386304;

        k_rms<<<2048, 256, 0, stream>>>(hx, norm1_w + d*HIDN, modd + 0*HIDN, hbf);
        k_gemm_qkv<<<dim3(27,16), 256, 0, stream>>>(hbf, wt_qkv, qkv_b + d*3456,
                cosb, sinb, qbf, kbf, vbf);
        k_attn_mfma<<<256, 512, 0, stream>>>(qbf, kbf, vbf, hbf);
        k_gemm32<<<dim3(9,64), 256, 0, stream>>>(hbf, wt_out,
                out_b + d*HIDN, hx, MTOK, HIDN, HIDN, modd + 1*HIDN);
        k_rms<<<2048, 256, 0, stream>>>(hx, norm2_w + d*HIDN, modd + 2*HIDN, hbf);
        k_gemm_bf16<2, __hip_bfloat16><<<dim3(48,16), 256, 0, stream>>>(hbf, wt_m12,
                mlp_b12 + d*6144, mhbf, MTOK, 6144, HIDN, nullptr);
        k_gemm32<<<dim3(9,64), 256, 0, stream>>>(mhbf, wt_m3,
                mlp_b3 + d*HIDN, hx, MTOK, HIDN, MLPM, modd + 3*HIDN);
    }
    k_final<<<2048, 256, 0, stream>>>(hx, fnorm_w, fmod, flin_w, flin_b, (float*)d_out);
}

// Round 19
// 972.464 us; speedup vs baseline: 1.0527x; 1.0527x over previous
//
#include <hip/hip_runtime.h>
#include <hip/hip_bf16.h>

#define HIDN 1152
#define NHEAD 16
#define HDIM 72
#define LTOK 1024
#define MTOK 2048
#define MLPM 3072

typedef short bf16x8 __attribute__((ext_vector_type(8)));
typedef float f32x4 __attribute__((ext_vector_type(4)));

__device__ __forceinline__ void gload16(const void* g, void* l) {
    __builtin_amdgcn_global_load_lds(
        (const __attribute__((address_space(1))) void*)g,
        (__attribute__((address_space(3))) void*)l,
        16, 0, 0);
}

__device__ __forceinline__ short bfbits(float f) {
    __hip_bfloat16 h = __float2bfloat16(f);
    return *(short*)&h;
}
__device__ __forceinline__ float bff(short s) {
    return __bfloat162float(*(__hip_bfloat16*)&s);
}

// XCD-aware bijective block remap (T1, m204 form; requires nwg % 8 == 0)
__device__ __forceinline__ void xcd_swizzle(int& bx, int& by) {
    int gx = gridDim.x;
    int wgid = blockIdx.y * gx + blockIdx.x;
    int cpx = (gx * gridDim.y) >> 3;
    int nid = (wgid & 7) * cpx + (wgid >> 3);
    bx = nid % gx;
    by = nid / gx;
}

// ---------------- patch embed: x (B,4,64,64) -> hx (2048,1152) bf16 ----------------
__global__ __launch_bounds__(256) void k_patch(const float* __restrict__ x,
        const float* __restrict__ pw, const float* __restrict__ pb,
        __hip_bfloat16* __restrict__ h) {
    int m = blockIdx.x;            // 0..2047
    int b = m >> 10, l = m & 1023;
    int si = l >> 5, sj = l & 31;
    __shared__ float toks[16];
    int tid = threadIdx.x;
    if (tid < 16) {
        int pi = tid >> 3, pj = (tid >> 2) & 1, c = tid & 3;
        toks[tid] = x[((size_t)(b*4 + c)*64 + si*2 + pi)*64 + sj*2 + pj];
    }
    __syncthreads();
    for (int o = tid; o < HIDN; o += 256) {
        float acc = pb[o];
        #pragma unroll
        for (int kk = 0; kk < 16; ++kk) acc += toks[kk] * pw[kk*HIDN + o];
        h[(size_t)m*HIDN + o] = __float2bfloat16(acc);
    }
}

// ------- temb1 = silu(timestep_emb @ w1 + b1): grid (9,2), 2-way K-split in-block -------
__global__ __launch_bounds__(256) void k_temb1_v2(const float* __restrict__ t,
        const float* __restrict__ w1, const float* __restrict__ b1,
        float* __restrict__ temb1) {
    int jt = blockIdx.x, b = blockIdx.y;
    int tid = threadIdx.x;
    __shared__ float emb[256];
    __shared__ float red[128];
    float tv = t[b];
    if (tid < 128) { float f = __expf(-logf(10000.f) * (float)tid / 128.f);        emb[tid] = cosf(tv * f); }
    else           { float f = __expf(-logf(10000.f) * (float)(tid - 128) / 128.f); emb[tid] = sinf(tv * f); }
    __syncthreads();
    int o = jt*128 + (tid & 127), s = tid >> 7;
    float acc = 0.f;
    for (int k = s*128; k < s*128 + 128; ++k) acc += emb[k] * w1[(size_t)k*HIDN + o];
    if (s) red[tid & 127] = acc;
    __syncthreads();
    if (!s) {
        float v = acc + red[tid] + b1[o];
        temb1[b*HIDN + o] = v / (1.f + __expf(-v));
    }
}

// ------- csilu stage 1: partial[kz][b][o] = temb1[b] @ w2[kz-slice]: grid (9,4) -------
__global__ __launch_bounds__(256) void k_csilu_s1(const float* __restrict__ temb1,
        const float* __restrict__ w2, float* __restrict__ csilup) {
    int jt = blockIdx.x, kz = blockIdx.y;
    int tid = threadIdx.x;
    __shared__ float t1s[2][288];
    __shared__ float red[2][128];
    for (int i = tid; i < 576; i += 256)
        t1s[i/288][i%288] = temb1[(i/288)*HIDN + kz*288 + (i%288)];
    __syncthreads();
    int o = jt*128 + (tid & 127), s = tid >> 7;
    float a0 = 0.f, a1 = 0.f;
    for (int i = s*144; i < s*144 + 144; ++i) {
        float wv = w2[(size_t)(kz*288 + i)*HIDN + o];
        a0 += t1s[0][i]*wv; a1 += t1s[1][i]*wv;
    }
    if (s) { red[0][tid & 127] = a0; red[1][tid & 127] = a1; }
    __syncthreads();
    if (!s) {
        csilup[(kz*2 + 0)*HIDN + o] = a0 + red[0][tid];
        csilup[(kz*2 + 1)*HIDN + o] = a1 + red[1][tid];
    }
}

// ------- csilu stage 2: reduce + b2 + y_table[y] + silu: grid (9,2) x 128 -------
__global__ __launch_bounds__(128) void k_csilu_s2(const float* __restrict__ csilup,
        const float* __restrict__ b2, const float* __restrict__ ytab,
        const int* __restrict__ y, float* __restrict__ csilu) {
    int o = blockIdx.x*128 + threadIdx.x;
    int b = blockIdx.y;
    float acc = b2[o] + ytab[(size_t)y[b]*HIDN + o];
    #pragma unroll
    for (int kz = 0; kz < 4; ++kz) acc += csilup[(kz*2 + b)*HIDN + o];
    csilu[b*HIDN + o] = acc / (1.f + __expf(-acc));
}

// ------- conditioning stage 1: all adaln (4 layers x 4608) + fadaln (2304) cols -------
__global__ __launch_bounds__(256) void k_cond_s1(const float* __restrict__ csilu,
        const float* __restrict__ adaln_w, const float* __restrict__ fadaln_w,
        float* __restrict__ condp) {
    int ct = blockIdx.x, kz = blockIdx.y;
    int tid = threadIdx.x;
    int c0 = ct*128;
    const float* Wb; int rstride;
    if (c0 < 18432) { int d = c0/4608; Wb = adaln_w + (size_t)d*HIDN*4608 + (c0 % 4608); rstride = 4608; }
    else            { Wb = fadaln_w + (c0 - 18432); rstride = 2304; }
    __shared__ float cs[2][288];
    __shared__ float red[2][128];
    for (int i = tid; i < 576; i += 256)
        cs[i/288][i%288] = csilu[(i/288)*HIDN + kz*288 + (i%288)];
    __syncthreads();
    int o = tid & 127, s = tid >> 7;
    float a0 = 0.f, a1 = 0.f;
    for (int i = s*144; i < s*144 + 144; ++i) {
        float wv = Wb[(size_t)(kz*288 + i)*rstride + o];
        a0 += cs[0][i]*wv; a1 += cs[1][i]*wv;
    }
    if (s) { red[0][o] = a0; red[1][o] = a1; }
    __syncthreads();
    if (!s) {
        condp[((size_t)kz*2 + 0)*20736 + c0 + o] = a0 + red[0][o];
        condp[((size_t)kz*2 + 1)*20736 + c0 + o] = a1 + red[1][o];
    }
}

// ------- conditioning stage 2: reduce 4 partials + bias -> modb / fmod: grid (81,2) -------
__global__ __launch_bounds__(256) void k_cond_s2(const float* __restrict__ condp,
        const float* __restrict__ adaln_b, const float* __restrict__ fadaln_b,
        float* __restrict__ modb, float* __restrict__ fmod) {
    int c = blockIdx.x*256 + threadIdx.x;
    int b = blockIdx.y;
    float acc = 0.f;
    #pragma unroll
    for (int kz = 0; kz < 4; ++kz) acc += condp[((size_t)kz*2 + b)*20736 + c];
    if (c < 18432) {
        int d = c/4608, j = c%4608;
        modb[((size_t)d*2 + b)*4608 + j] = acc + adaln_b[(size_t)d*4608 + j];
    } else {
        int j = c - 18432;
        fmod[(size_t)b*2304 + j] = acc + fadaln_b[j];
    }
}

// ---------------- RoPE tables (1024, 72) ----------------
__global__ __launch_bounds__(256) void k_rope(float* __restrict__ cosb, float* __restrict__ sinb) {
    int idx = blockIdx.x*256 + threadIdx.x;
    if (idx >= LTOK*HDIM) return;
    int l = idx / HDIM, dd = idx % HDIM;
    int i = l >> 5, j = l & 31;
    int pos = (dd < 36) ? i : j;
    int mm = ((dd < 36) ? dd : dd - 36) >> 1;
    float f = __expf(-logf(10000.f) * (float)mm / 18.f);
    float fr = (float)pos * f;
    cosb[idx] = cosf(fr);
    sinb[idx] = sinf(fr);
}

// ---------------- rmsnorm * (1 + s_mod): bf16 hx -> bf16 out ----------------
__global__ __launch_bounds__(256) void k_rms(const __hip_bfloat16* __restrict__ hx,
        const float* __restrict__ nw, const float* __restrict__ smod,
        __hip_bfloat16* __restrict__ outp) {
    int m = blockIdx.x; int b = m >> 10;
    int tid = threadIdx.x;
    const bf16x8* row8 = (const bf16x8*)(hx + (size_t)m*HIDN);
    bool act = tid < 144;              // 144 * 8 = 1152
    float vals[8];
    float part = 0.f;
    if (act) {
        bf16x8 v = row8[tid];
        #pragma unroll
        for (int i = 0; i < 8; ++i) { float f = bff(v[i]); vals[i] = f; part += f*f; }
    }
    for (int off = 32; off; off >>= 1) part += __shfl_xor(part, off);
    __shared__ float wsum[4];
    if ((tid & 63) == 0) wsum[tid >> 6] = part;
    __syncthreads();
    float rs = rsqrtf((wsum[0]+wsum[1]+wsum[2]+wsum[3]) * (1.f/HIDN) + 1e-6f);
    if (act) {
        const float* nwp = nw + tid*8;
        const float* sbp = smod + (size_t)b*4608 + tid*8;
        bf16x8 o;
        #pragma unroll
        for (int i = 0; i < 8; ++i)
            o[i] = bfbits(vals[i] * rs * nwp[i] * (1.f + sbp[i]));
        *(bf16x8*)(outp + (size_t)m*HIDN + tid*8) = o;
    }
}

// ------- cast+transpose ALL layer weights, 128k x 64n tiles, 256B reads AND writes -------
__global__ __launch_bounds__(256) void k_castT_all(
        const float* __restrict__ qkv_w, const float* __restrict__ out_w,
        const float* __restrict__ m12_w, const float* __restrict__ m3_w,
        __hip_bfloat16* __restrict__ wtb) {
    __shared__ float tile[128][65];
    int bid = blockIdx.x;
    int layer = bid / 1944, r = bid % 1944;
    const float* W; __hip_bfloat16* Wt; int K, N, nt, t; bool glu = false;
    __hip_bfloat16* bl = wtb + (size_t)layer*15925248;
    if (r < 486)       { t = r;        nt = 54; K = 1152; N = 3456; W = qkv_w + (size_t)layer*K*N; Wt = bl; }
    else if (r < 648)  { t = r - 486;  nt = 18; K = 1152; N = 1152; W = out_w + (size_t)layer*K*N; Wt = bl + 3981312; }
    else if (r < 1512) { t = r - 648;  nt = 96; K = 1152; N = 6144; W = m12_w + (size_t)layer*K*N; Wt = bl + 5308416; glu = true; }
    else               { t = r - 1512; nt = 18; K = 3072; N = 1152; W = m3_w  + (size_t)layer*K*N; Wt = bl + 12386304; }
    int n0 = (t % nt)*64, k0 = (t / nt)*128;
    int tid = threadIdx.x;
    int rr = tid >> 4, c4 = (tid & 15)*4;
    #pragma unroll
    for (int p = 0; p < 8; ++p) {
        int kk = p*16 + rr;
        float4 v = *(const float4*)(W + (size_t)(k0+kk)*N + n0 + c4);
        tile[kk][c4+0] = v.x; tile[kk][c4+1] = v.y; tile[kk][c4+2] = v.z; tile[kk][c4+3] = v.w;
    }
    __syncthreads();
    int seg = tid & 15, nn0 = tid >> 4;
    #pragma unroll
    for (int p = 0; p < 4; ++p) {
        int nn = p*16 + nn0;
        bf16x8 o;
        #pragma unroll
        for (int j = 0; j < 8; ++j) o[j] = bfbits(tile[seg*8 + j][nn]);
        int ng = n0 + nn;
        int np = glu ? ((ng < 3072) ? 2*ng : 2*(ng - 3072) + 1) : ng;
        *(bf16x8*)(Wt + (size_t)np*K + k0 + seg*8) = o;
    }
}

// ---------------- bf16 MFMA GEMM 128x128, double-buffered ------
// EPI 0: C = bf16(A@W^T + bias)   EPI 2: GLU interleaved -> bf16(silu(x1)*x2), ld=N/2
template<int EPI, typename OutT>
__global__ __launch_bounds__(256) void k_gemm_bf16(
        const __hip_bfloat16* __restrict__ A,
        const __hip_bfloat16* __restrict__ Wt,
        const float* __restrict__ bias,
        OutT* __restrict__ C, int M, int N, int K,
        const float* __restrict__ gate) {
    __shared__ __hip_bfloat16 Asm[2][128*64];
    __shared__ __hip_bfloat16 Bsm[2][128*64];
    int bx, by; xcd_swizzle(bx, by);
    int tid = threadIdx.x;
    int lane = tid & 63, w = tid >> 6;
    int wr = w >> 1, wc = w & 1;
    int m0 = by * 128, n0 = bx * 128;
    f32x4 acc[4][4] = {};
    int lr = lane >> 3, ls = lane & 7;
    int swz = ls ^ (lr & 7);
    int x7 = lane & 7;
    const __hip_bfloat16* Ag = A  + (size_t)(m0 + lr)*K + swz*8;
    const __hip_bfloat16* Bg = Wt + (size_t)(n0 + lr)*K + swz*8;
    int nk = K >> 6;
    #pragma unroll
    for (int i = 0; i < 4; ++i) {
        int seg = w*4 + i;
        gload16(Ag + (size_t)(seg*8)*K, (char*)&Asm[0][0] + seg*1024);
        gload16(Bg + (size_t)(seg*8)*K, (char*)&Bsm[0][0] + seg*1024);
    }
    __syncthreads();
    for (int t = 0; t < nk; ++t) {
        int cur = t & 1;
        if (t + 1 < nk) {
            int k1 = (t + 1) << 6;
            #pragma unroll
            for (int i = 0; i < 4; ++i) {
                int seg = w*4 + i;
                gload16(Ag + (size_t)(seg*8)*K + k1, (char*)&Asm[cur^1][0] + seg*1024);
                gload16(Bg + (size_t)(seg*8)*K + k1, (char*)&Bsm[cur^1][0] + seg*1024);
            }
        }
        const __hip_bfloat16* Ac = Asm[cur];
        const __hip_bfloat16* Bc = Bsm[cur];
        __builtin_amdgcn_s_setprio(1);
        #pragma unroll
        for (int kk = 0; kk < 2; ++kk) {
            bf16x8 af[4], bfr[4];
            #pragma unroll
            for (int m = 0; m < 4; ++m) {
                int row = wr*64 + m*16 + (lane&15);
                af[m] = *(const bf16x8*)(Ac + row*64 + (((kk*4 + (lane>>4)) ^ x7) * 8));
            }
            #pragma unroll
            for (int n = 0; n < 4; ++n) {
                int col = wc*64 + n*16 + (lane&15);
                bfr[n] = *(const bf16x8*)(Bc + col*64 + (((kk*4 + (lane>>4)) ^ x7) * 8));
            }
            #pragma unroll
            for (int m = 0; m < 4; ++m)
                #pragma unroll
                for (int n = 0; n < 4; ++n)
                    acc[m][n] = __builtin_amdgcn_mfma_f32_16x16x32_bf16(af[m], bfr[n], acc[m][n], 0, 0, 0);
        }
        __builtin_amdgcn_s_setprio(0);
        __syncthreads();
    }
    int r0 = (lane >> 4) * 4;
    int ccol = lane & 15;
    #pragma unroll
    for (int m = 0; m < 4; ++m) {
        #pragma unroll
        for (int rr = 0; rr < 4; ++rr) {
            int row = m0 + wr*64 + m*16 + r0 + rr;
            #pragma unroll
            for (int n = 0; n < 4; ++n) {
                int col = n0 + wc*64 + n*16 + ccol;
                if (EPI == 0) {
                    float val = acc[m][n][rr] + bias[col];
                    C[(size_t)row*N + col] = (OutT)__float2bfloat16(val);
                } else {
                    float val = acc[m][n][rr] + bias[(col & 1) ? 3072 + (col >> 1) : (col >> 1)];
                    float other = __shfl_xor(val, 1);
                    if (!(lane & 1)) {
                        float res = val / (1.f + __expf(-val)) * other;
                        ((__hip_bfloat16*)C)[(size_t)row*(N>>1) + (col>>1)] = __float2bfloat16(res);
                    }
                }
            }
        }
    }
}

// ------- qkv GEMM 128x128, double-buffered, fused RoPE + q/k/v-split epilogue -------
__global__ __launch_bounds__(256) void k_gemm_qkv(
        const __hip_bfloat16* __restrict__ A,
        const __hip_bfloat16* __restrict__ Wt,
        const float* __restrict__ bias,
        const float* __restrict__ cosb, const float* __restrict__ sinb,
        __hip_bfloat16* __restrict__ q, __hip_bfloat16* __restrict__ k,
        __hip_bfloat16* __restrict__ v) {
    const int N = 3456, K = HIDN;
    __shared__ __hip_bfloat16 Asm[2][128*64];
    __shared__ __hip_bfloat16 Bsm[2][128*64];
    int bx, by; xcd_swizzle(bx, by);
    int tid = threadIdx.x;
    int lane = tid & 63, w = tid >> 6;
    int wr = w >> 1, wc = w & 1;
    int m0 = by * 128, n0 = bx * 128;
    f32x4 acc[4][4] = {};
    int lr = lane >> 3, ls = lane & 7;
    int swz = ls ^ (lr & 7);
    int x7 = lane & 7;
    const __hip_bfloat16* Ag = A  + (size_t)(m0 + lr)*K + swz*8;
    const __hip_bfloat16* Bg = Wt + (size_t)(n0 + lr)*K + swz*8;
    const int nk = K >> 6;
    #pragma unroll
    for (int i = 0; i < 4; ++i) {
        int seg = w*4 + i;
        gload16(Ag + (size_t)(seg*8)*K, (char*)&Asm[0][0] + seg*1024);
        gload16(Bg + (size_t)(seg*8)*K, (char*)&Bsm[0][0] + seg*1024);
    }
    __syncthreads();
    for (int t = 0; t < nk; ++t) {
        int cur = t & 1;
        if (t + 1 < nk) {
            int k1 = (t + 1) << 6;
            #pragma unroll
            for (int i = 0; i < 4; ++i) {
                int seg = w*4 + i;
                gload16(Ag + (size_t)(seg*8)*K + k1, (char*)&Asm[cur^1][0] + seg*1024);
                gload16(Bg + (size_t)(seg*8)*K + k1, (char*)&Bsm[cur^1][0] + seg*1024);
            }
        }
        const __hip_bfloat16* Ac = Asm[cur];
        const __hip_bfloat16* Bc = Bsm[cur];
        __builtin_amdgcn_s_setprio(1);
        #pragma unroll
        for (int kk = 0; kk < 2; ++kk) {
            bf16x8 af[4], bfr[4];
            #pragma unroll
            for (int m = 0; m < 4; ++m) {
                int row = wr*64 + m*16 + (lane&15);
                af[m] = *(const bf16x8*)(Ac + row*64 + (((kk*4 + (lane>>4)) ^ x7) * 8));
            }
            #pragma unroll
            for (int n = 0; n < 4; ++n) {
                int col = wc*64 + n*16 + (lane&15);
                bfr[n] = *(const bf16x8*)(Bc + col*64 + (((kk*4 + (lane>>4)) ^ x7) * 8));
            }
            #pragma unroll
            for (int m = 0; m < 4; ++m)
                #pragma unroll
                for (int n = 0; n < 4; ++n)
                    acc[m][n] = __builtin_amdgcn_mfma_f32_16x16x32_bf16(af[m], bfr[n], acc[m][n], 0, 0, 0);
        }
        __builtin_amdgcn_s_setprio(0);
        __syncthreads();
    }
    int r0 = (lane >> 4) * 4;
    int ccol = lane & 15;
    int sec = n0 / 1152;            // 0=q 1=k 2=v, block-uniform
    int rembase = n0 - sec*1152 + wc*64;
    #pragma unroll
    for (int m = 0; m < 4; ++m) {
        #pragma unroll
        for (int rr = 0; rr < 4; ++rr) {
            int row = m0 + wr*64 + m*16 + r0 + rr;
            int b = row >> 10, l = row & 1023;
            #pragma unroll
            for (int n = 0; n < 4; ++n) {
                int rem = rembase + n*16 + ccol;
                int h = rem / HDIM, d = rem % HDIM;
                float val = acc[m][n][rr] + bias[sec*1152 + rem];
                if (sec == 2) {
                    v[((size_t)(b*NHEAD + h)*HDIM + d)*LTOK + l] = __float2bfloat16(val);
                } else {
                    float c = cosb[l*HDIM + d], s = sinb[l*HDIM + d];
                    float other = __shfl_xor(val, 1);
                    float res = (d & 1) ? (val*c + other*s) : (val*c - other*s);
                    __hip_bfloat16 hv = __float2bfloat16(res);
                    size_t dst = ((size_t)(b*NHEAD + h)*LTOK + l)*HDIM + d;
                    if (sec == 0) q[dst] = hv; else k[dst] = hv;
                }
            }
        }
    }
}

// ------- bf16 MFMA GEMM 32x128 tile (max occupancy for N=1152), EPI1 bf16 RMW ---
__global__ __launch_bounds__(256) void k_gemm32(
        const __hip_bfloat16* __restrict__ A,
        const __hip_bfloat16* __restrict__ Wt,
        const float* __restrict__ bias,
        __hip_bfloat16* __restrict__ C, int M, int N, int K,
        const float* __restrict__ gate) {
    __shared__ __hip_bfloat16 Asm[2][32*64];
    __shared__ __hip_bfloat16 Bsm[2][128*64];
    int bx, by; xcd_swizzle(bx, by);
    int tid = threadIdx.x;
    int lane = tid & 63, w = tid >> 6;
    int wr = w >> 1, wc = w & 1;
    int m0 = by * 32, n0 = bx * 128;
    f32x4 acc[4] = {};
    int lr = lane >> 3, ls = lane & 7;
    int swz = ls ^ (lr & 7);
    int x7 = lane & 7;
    const __hip_bfloat16* Ag = A  + (size_t)(m0 + lr)*K + swz*8;
    const __hip_bfloat16* Bg = Wt + (size_t)(n0 + lr)*K + swz*8;
    int nk = K >> 6;
    gload16(Ag + (size_t)(w*8)*K, (char*)&Asm[0][0] + w*1024);
    #pragma unroll
    for (int i = 0; i < 4; ++i) {
        int seg = w*4 + i;
        gload16(Bg + (size_t)(seg*8)*K, (char*)&Bsm[0][0] + seg*1024);
    }
    __syncthreads();
    for (int t = 0; t < nk; ++t) {
        int cur = t & 1;
        if (t + 1 < nk) {
            int k1 = (t + 1) << 6;
            gload16(Ag + (size_t)(w*8)*K + k1, (char*)&Asm[cur^1][0] + w*1024);
            #pragma unroll
            for (int i = 0; i < 4; ++i) {
                int seg = w*4 + i;
                gload16(Bg + (size_t)(seg*8)*K + k1, (char*)&Bsm[cur^1][0] + seg*1024);
            }
        }
        const __hip_bfloat16* Ac = Asm[cur];
        const __hip_bfloat16* Bc = Bsm[cur];
        __builtin_amdgcn_s_setprio(1);
        #pragma unroll
        for (int kk = 0; kk < 2; ++kk) {
            int row = wr*16 + (lane&15);
            bf16x8 af = *(const bf16x8*)(Ac + row*64 + (((kk*4 + (lane>>4)) ^ x7) * 8));
            #pragma unroll
            for (int n = 0; n < 4; ++n) {
                int col = wc*64 + n*16 + (lane&15);
                bf16x8 bfr = *(const bf16x8*)(Bc + col*64 + (((kk*4 + (lane>>4)) ^ x7) * 8));
                acc[n] = __builtin_amdgcn_mfma_f32_16x16x32_bf16(af, bfr, acc[n], 0, 0, 0);
            }
        }
        __builtin_amdgcn_s_setprio(0);
        __syncthreads();
    }
    int r0 = (lane >> 4) * 4;
    int ccol = lane & 15;
    #pragma unroll
    for (int rr = 0; rr < 4; ++rr) {
        int row = m0 + wr*16 + r0 + rr;
        int bi = row >> 10;
        #pragma unroll
        for (int n = 0; n < 4; ++n) {
            int col = n0 + wc*64 + n*16 + ccol;
            float val = acc[n][rr] + bias[col];
            size_t idx = (size_t)row*N + col;
            float prev = __bfloat162float(C[idx]);
            C[idx] = __float2bfloat16(prev + gate[(size_t)bi*4608 + col] * val);
        }
    }
}

// ------- MFMA flash attention: XCD-local head mapping + defer-max (T13) ---------
__global__ __launch_bounds__(512) void k_attn_mfma(
        const __hip_bfloat16* __restrict__ q,
        const __hip_bfloat16* __restrict__ k,
        const __hip_bfloat16* __restrict__ vt,
        __hip_bfloat16* __restrict__ o) {
    int x = blockIdx.x;
    int head_id = (x & 7)*4 + (x >> 6);   // 0..31; constant per XCD slice
    int qt = (x >> 3) & 7;
    int b = head_id >> 4, h = head_id & 15;
    const float scale = 0.117851130f;   // 1/sqrt(72)
    __shared__ __hip_bfloat16 Ksm[2][64*72];
    __shared__ __hip_bfloat16 Vsm[2][72*64];
    __shared__ __hip_bfloat16 Psm[8][16*72];
    int tid = threadIdx.x, lane = tid & 63, w = tid >> 6;   // w: 0..7
    int l15 = lane & 15, g = lane >> 4;
    const __hip_bfloat16* qg = q  + ((size_t)(b*NHEAD + h)*LTOK + qt*128)*HDIM;
    const __hip_bfloat16* kg = k  + (size_t)(b*NHEAD + h)*LTOK*HDIM;
    const __hip_bfloat16* vg = vt + (size_t)(b*NHEAD + h)*HDIM*LTOK;
    const bf16x8 z = {};

    bf16x8 qf[3];
    {
        const __hip_bfloat16* qrow = qg + (w*16 + l15)*HDIM;
        qf[0] = *(const bf16x8*)(qrow + g*8);
        qf[1] = *(const bf16x8*)(qrow + 32 + g*8);
        qf[2] = (g == 0) ? *(const bf16x8*)(qrow + 64) : z;
    }
    int vsw  = ((lane & 7) ^ (lane >> 3)) * 8;
    int vrow = lane >> 3;

    f32x4 oacc[5] = {};
    float mold[4] = {-1e30f, -1e30f, -1e30f, -1e30f};
    float lsum[4] = {};

    {
        for (int s = w; s < 9; s += 8) {
            gload16(kg + s*512 + lane*8, (char*)&Ksm[0][0] + s*1024);
            gload16(vg + (size_t)(s*8 + vrow)*LTOK + vsw, (char*)&Vsm[0][0] + s*1024);
        }
    }
    __syncthreads();

    for (int kt2 = 0; kt2 < 16; ++kt2) {
        int cur = kt2 & 1;
        if (kt2 < 15) {
            const __hip_bfloat16* ktg = kg + (size_t)(kt2+1)*64*HDIM;
            const __hip_bfloat16* vtg = vg + (kt2+1)*64;
            for (int s = w; s < 9; s += 8) {
                gload16(ktg + s*512 + lane*8, (char*)&Ksm[cur^1][0] + s*1024);
                gload16(vtg + (size_t)(s*8 + vrow)*LTOK + vsw, (char*)&Vsm[cur^1][0] + s*1024);
            }
        }
        const __hip_bfloat16* Kc = Ksm[cur];
        const __hip_bfloat16* Vc = Vsm[cur];
        f32x4 st[4] = {};
        __builtin_amdgcn_s_setprio(1);
        #pragma unroll
        for (int t = 0; t < 4; ++t) {
            const __hip_bfloat16* krow = Kc + (t*16 + l15)*72;
            bf16x8 kf0 = *(const bf16x8*)(krow + g*8);
            bf16x8 kf1 = *(const bf16x8*)(krow + 32 + g*8);
            bf16x8 kf2 = (g == 0) ? *(const bf16x8*)(krow + 64) : z;
            st[t] = __builtin_amdgcn_mfma_f32_16x16x32_bf16(qf[0], kf0, st[t], 0, 0, 0);
            st[t] = __builtin_amdgcn_mfma_f32_16x16x32_bf16(qf[1], kf1, st[t], 0, 0, 0);
            st[t] = __builtin_amdgcn_mfma_f32_16x16x32_bf16(qf[2], kf2, st[t], 0, 0, 0);
        }
        __builtin_amdgcn_s_setprio(0);
        float mtr[4];
        #pragma unroll
        for (int r = 0; r < 4; ++r) {
            float mt = fmaxf(fmaxf(st[0][r], st[1][r]), fmaxf(st[2][r], st[3][r]));
            mt = fmaxf(mt, __shfl_xor(mt, 1));
            mt = fmaxf(mt, __shfl_xor(mt, 2));
            mt = fmaxf(mt, __shfl_xor(mt, 4));
            mt = fmaxf(mt, __shfl_xor(mt, 8));
            mtr[r] = mt;
        }
        bool need = false;
        #pragma unroll
        for (int r = 0; r < 4; ++r) need |= (mtr[r] - mold[r]) * scale > 8.f;
        if (__any(need)) {
            #pragma unroll
            for (int r = 0; r < 4; ++r) {
                float mn = fmaxf(mold[r], mtr[r]);
                float corr = __expf((mold[r] - mn) * scale);
                mold[r] = mn;
                lsum[r] *= corr;
                #pragma unroll
                for (int dt = 0; dt < 5; ++dt) oacc[dt][r] *= corr;
            }
        }
        #pragma unroll
        for (int r = 0; r < 4; ++r) {
            float rs = 0.f;
            #pragma unroll
            for (int t = 0; t < 4; ++t) {
                float p = __expf((st[t][r] - mold[r]) * scale);   // bounded by e^8
                rs += p;
                Psm[w][(g*4 + r)*72 + t*16 + l15] = __float2bfloat16(p);
            }
            rs += __shfl_xor(rs, 1);
            rs += __shfl_xor(rs, 2);
            rs += __shfl_xor(rs, 4);
            rs += __shfl_xor(rs, 8);
            lsum[r] += rs;
        }
        bf16x8 pa0 = *(const bf16x8*)(&Psm[w][l15*72 + g*8]);
        bf16x8 pa1 = *(const bf16x8*)(&Psm[w][l15*72 + 32 + g*8]);
        int cswz = (l15 & 7)*8;
        __builtin_amdgcn_s_setprio(1);
        #pragma unroll
        for (int dt = 0; dt < 5; ++dt) {
            int row = dt*16 + l15;
            bool valid = (dt < 4) | (l15 < 8);
            bf16x8 vf0 = valid ? *(const bf16x8*)(Vc + row*64 + ((g*8) ^ cswz)) : z;
            bf16x8 vf1 = valid ? *(const bf16x8*)(Vc + row*64 + ((32 + g*8) ^ cswz)) : z;
            oacc[dt] = __builtin_amdgcn_mfma_f32_16x16x32_bf16(pa0, vf0, oacc[dt], 0, 0, 0);
            oacc[dt] = __builtin_amdgcn_mfma_f32_16x16x32_bf16(pa1, vf1, oacc[dt], 0, 0, 0);
        }
        __builtin_amdgcn_s_setprio(0);
        __syncthreads();
    }
    #pragma unroll
    for (int r = 0; r < 4; ++r) {
        float inv = 1.f / lsum[r];
        int row = qt*128 + w*16 + g*4 + r;
        __hip_bfloat16* op = o + ((size_t)b*LTOK + row)*HIDN + h*HDIM;
        #pragma unroll
        for (int dt = 0; dt < 5; ++dt) {
            int d = dt*16 + l15;
            if (d < HDIM) op[d] = __float2bfloat16(oacc[dt][r] * inv);
        }
    }
}

// ---------------- final norm + linear + unpatchify (bf16 hx) ----------------
__global__ __launch_bounds__(256) void k_final(const __hip_bfloat16* __restrict__ hx,
        const float* __restrict__ fnw, const float* __restrict__ fmod,
        const float* __restrict__ flw, const float* __restrict__ flb,
        float* __restrict__ out) {
    int m = blockIdx.x; int b = m >> 10, l = m & 1023;
    int tid = threadIdx.x;
    const bf16x8* row8 = (const bf16x8*)(hx + (size_t)m*HIDN);
    bool act = tid < 144;
    float vals[8];
    float part = 0.f;
    if (act) {
        bf16x8 v = row8[tid];
        #pragma unroll
        for (int i = 0; i < 8; ++i) { float f = bff(v[i]); vals[i] = f; part += f*f; }
    }
    for (int off = 32; off; off >>= 1) part += __shfl_xor(part, off);
    __shared__ float wsum[4];
    __shared__ float hfs[HIDN];
    __shared__ float red[4][16];
    if ((tid & 63) == 0) wsum[tid >> 6] = part;
    __syncthreads();
    float rs = rsqrtf((wsum[0]+wsum[1]+wsum[2]+wsum[3]) * (1.f/HIDN) + 1e-6f);
    if (act) {
        const float* fm = fmod + (size_t)b*2304;
        #pragma unroll
        for (int i = 0; i < 8; ++i) {
            int j = tid*8 + i;
            hfs[j] = vals[i] * rs * fnw[j] * (1.f + fm[HIDN + j]) + fm[j];
        }
    }
    __syncthreads();
    float pacc[16] = {};
    for (int j = tid; j < HIDN; j += 256) {
        float hv = hfs[j];
        #pragma unroll
        for (int kk = 0; kk < 16; ++kk) pacc[kk] += hv * flw[j*16 + kk];
    }
    #pragma unroll
    for (int kk = 0; kk < 16; ++kk)
        for (int off = 32; off; off >>= 1) pacc[kk] += __shfl_xor(pacc[kk], off);
    if ((tid & 63) == 0) {
        int w = tid >> 6;
        #pragma unroll
        for (int kk = 0; kk < 16; ++kk) red[w][kk] = pacc[kk];
    }
    __syncthreads();
    if (tid < 16) {
        float val = red[0][tid] + red[1][tid] + red[2][tid] + red[3][tid] + flb[tid];
        int pi = tid >> 3, pj = (tid >> 2) & 1, c = tid & 3;
        int si = l >> 5, sj = l & 31;
        out[((size_t)(b*4 + c)*64 + si*2 + pi)*64 + sj*2 + pj] = val;
    }
}

extern "C" void kernel_launch(void* const* d_in, const int* in_sizes, int n_in,
                              void* d_out, int out_size, void* d_ws, size_t ws_size,
                              hipStream_t stream) {
    const float* x        = (const float*)d_in[0];
    const float* t        = (const float*)d_in[1];
    const int*   y        = (const int*)  d_in[2];
    const float* patch_w  = (const float*)d_in[3];
    const float* patch_b  = (const float*)d_in[4];
    const float* t_w1     = (const float*)d_in[5];
    const float* t_b1     = (const float*)d_in[6];
    const float* t_w2     = (const float*)d_in[7];
    const float* t_b2     = (const float*)d_in[8];
    const float* y_table  = (const float*)d_in[9];
    const float* norm1_w  = (const float*)d_in[10];
    const float* qkv_w    = (const float*)d_in[11];
    const float* qkv_b    = (const float*)d_in[12];
    const float* out_w    = (const float*)d_in[13];
    const float* out_b    = (const float*)d_in[14];
    const float* norm2_w  = (const float*)d_in[15];
    const float* mlp_w12  = (const float*)d_in[16];
    const float* mlp_b12  = (const float*)d_in[17];
    const float* mlp_w3   = (const float*)d_in[18];
    const float* mlp_b3   = (const float*)d_in[19];
    const float* adaln_w  = (const float*)d_in[20];
    const float* adaln_b  = (const float*)d_in[21];
    const float* fnorm_w  = (const float*)d_in[22];
    const float* fadaln_w = (const float*)d_in[23];
    const float* fadaln_b = (const float*)d_in[24];
    const float* flin_w   = (const float*)d_in[25];
    const float* flin_b   = (const float*)d_in[26];

    char* base = (char*)d_ws;
    __hip_bfloat16* hx    = (__hip_bfloat16*)(base);              //  4,718,592 B (bf16 residual)
    __hip_bfloat16* qbf   = (__hip_bfloat16*)(base + 34603008);   //  4,718,592 B
    __hip_bfloat16* kbf   = (__hip_bfloat16*)(base + 39321600);   //  4,718,592 B
    __hip_bfloat16* vbf   = (__hip_bfloat16*)(base + 44040192);   //  4,718,592 B (B,NH,72,L)
    __hip_bfloat16* hbf   = (__hip_bfloat16*)(base + 48758784);   //  4,718,592 B
    __hip_bfloat16* mhbf  = qbf;                                  // GLU out aliases q/k (consumed)
    __hip_bfloat16* wtb   = (__hip_bfloat16*)(base + 53477376);   // 127,401,984 B (4 layers)
    float* temb1 = (float*)(base + 180879360);       // 9216 B
    float* csilu = (float*)(base + 180888576);       // 9216 B
    float* modb  = (float*)(base + 180897792);       // 147456 B [4][2][4608]
    float* fmod  = (float*)(base + 181045248);       // 18432 B  [2][2304]
    float* cosb  = (float*)(base + 181063680);       // 294912 B
    float* sinb  = (float*)(base + 181358592);       // 294912 B
    float* condp = (float*)(base + 181653504);       // 663552 B [4][2][20736]
    float* csilup= (float*)(base + 182317056);       // 36864 B
    // total ~182.4 MB

    k_patch<<<2048, 256, 0, stream>>>(x, patch_w, patch_b, hx);
    k_temb1_v2<<<dim3(9,2), 256, 0, stream>>>(t, t_w1, t_b1, temb1);
    k_csilu_s1<<<dim3(9,4), 256, 0, stream>>>(temb1, t_w2, csilup);
    k_csilu_s2<<<dim3(9,2), 128, 0, stream>>>(csilup, t_b2, y_table, y, csilu);
    k_cond_s1<<<dim3(162,4), 256, 0, stream>>>(csilu, adaln_w, fadaln_w, condp);
    k_cond_s2<<<dim3(81,2), 256, 0, stream>>>(condp, adaln_b, fadaln_b, modb, fmod);
    k_rope<<<288, 256, 0, stream>>>(cosb, sinb);
    k_castT_all<<<7776, 256, 0, stream>>>(qkv_w, out_w, mlp_w12, mlp_w3, wtb);

    for (int d = 0; d < 4; ++d) {
        const float* modd = modb + (size_t)d*2*4608;
        __hip_bfloat16* wl = wtb + (size_t)d*15925248;
        __hip_bfloat16* wt_qkv = wl;
        __hip_bfloat16* wt_out = wl + 3981312;
        __hip_bfloat16* wt_m12 = wl + 5308416;
        __hip_bfloat16* wt_m3  = wl + 12386304;

        k_rms<<<2048, 256, 0, stream>>>(hx, norm1_w + d*HIDN, modd + 0*HIDN, hbf);
        k_gemm_qkv<<<dim3(27,16), 256, 0, stream>>>(hbf, wt_qkv, qkv_b + d*3456,
                cosb, sinb, qbf, kbf, vbf);
        k_attn_mfma<<<256, 512, 0, stream>>>(qbf, kbf, vbf, hbf);
        k_gemm32<<<dim3(9,64), 256, 0, stream>>>(hbf, wt_out,
                out_b + d*HIDN, hx, MTOK, HIDN, HIDN, modd + 1*HIDN);
        k_rms<<<2048, 256, 0, stream>>>(hx, norm2_w + d*HIDN, modd + 2*HIDN, hbf);
        k_gemm_bf16<2, __hip_bfloat16><<<dim3(48,16), 256, 0, stream>>>(hbf, wt_m12,
                mlp_b12 + d*6144, mhbf, MTOK, 6144, HIDN, nullptr);
        k_gemm32<<<dim3(9,64), 256, 0, stream>>>(mhbf, wt_m3,
                mlp_b3 + d*HIDN, hx, MTOK, HIDN, MLPM, modd + 3*HIDN);
    }
    k_final<<<2048, 256, 0, stream>>>(hx, fnorm_w, fmod, flin_w, flin_b, (float*)d_out);
}